// Round 12
// baseline (173.811 us; speedup 1.0000x reference)
//
#include <hip/hip_runtime.h>
#include <math.h>

#define NB 2
#define NS 8192
#define NE 128
#define NROWS (NB * NS)

typedef __attribute__((ext_vector_type(8))) short s8v;    // 8 bf16 MFMA frag
typedef __attribute__((ext_vector_type(16))) float fx16;  // 32x32 accumulator
typedef __attribute__((address_space(1))) const unsigned char as1c;
typedef __attribute__((address_space(3))) unsigned char as3t;

static __device__ __forceinline__ unsigned int pkbf(float a, float b) {
    unsigned int ua = __float_as_uint(a), ub = __float_as_uint(b);
    ua += 0x7FFFu + ((ua >> 16) & 1u);
    ub += 0x7FFFu + ((ub >> 16) & 1u);
    return (ua >> 16) | (ub & 0xFFFF0000u);
}
// truncating pack: (b_hi16<<16)|a_hi16 in ONE v_perm_b32
static __device__ __forceinline__ unsigned int pkhi(float a, float b) {
    return __builtin_amdgcn_perm(__float_as_uint(a), __float_as_uint(b), 0x03020706u);
}

// ---------------------------------------------------------------------------
// QKV projection via 3-term compensated bf16 MFMA, fused x hi/lo split,
// per-wave LDS-transposed epilogue -> fully coalesced 16B stores.
// grid (128, 3, 2), block 256. Q pre-scaled by 1/sqrt(E).
// ---------------------------------------------------------------------------
__global__ __launch_bounds__(256, 2)
void qkv_kernel(const float* __restrict__ x,
                const float* __restrict__ Wq, const float* __restrict__ bq,
                const float* __restrict__ Wk, const float* __restrict__ bk,
                const float* __restrict__ Wv, const float* __restrict__ bv,
                unsigned short* __restrict__ qkv)
{
    __shared__ unsigned short WhL[64 * 136];
    __shared__ unsigned short WlL[64 * 136];
    __shared__ unsigned short stg[4 * 2560];   // per-wave epilogue staging

    const int t    = threadIdx.x;
    const int rblk = blockIdx.x * 128;
    const int mat  = blockIdx.y;
    const int o0   = blockIdx.z * 64;

    const float* W    = (mat == 0) ? Wq : (mat == 1) ? Wk : Wv;
    const float* bias = (mat == 0) ? bq : (mat == 1) ? bk : bv;
    unsigned short* out = qkv + (size_t)mat * NROWS * NE;
    const float osc = (mat == 0) ? 0.08838834764831845f : 1.0f;   // 1/sqrt(128)

    // ---- stage W half hi/lo into LDS ----
    {
        const int r = t >> 2, cg = (t & 3) * 32;
        #pragma unroll
        for (int j = 0; j < 4; ++j) {
            const float* wp = &W[(size_t)(o0 + r) * NE + cg + j * 8];
            float4 a = *(const float4*)wp;
            float4 b = *(const float4*)(wp + 4);
            unsigned int h0 = pkbf(a.x, a.y), h1 = pkbf(a.z, a.w);
            unsigned int h2 = pkbf(b.x, b.y), h3 = pkbf(b.z, b.w);
            *(uint4*)&WhL[r * 136 + cg + j * 8] = make_uint4(h0, h1, h2, h3);
            float l0 = a.x - __uint_as_float(h0 << 16);
            float l1 = a.y - __uint_as_float(h0 & 0xFFFF0000u);
            float l2 = a.z - __uint_as_float(h1 << 16);
            float l3 = a.w - __uint_as_float(h1 & 0xFFFF0000u);
            float l4 = b.x - __uint_as_float(h2 << 16);
            float l5 = b.y - __uint_as_float(h2 & 0xFFFF0000u);
            float l6 = b.z - __uint_as_float(h3 << 16);
            float l7 = b.w - __uint_as_float(h3 & 0xFFFF0000u);
            *(uint4*)&WlL[r * 136 + cg + j * 8] =
                make_uint4(pkbf(l0, l1), pkbf(l2, l3), pkbf(l4, l5), pkbf(l6, l7));
        }
    }
    __syncthreads();

    const int w = t >> 6, lane = t & 63, lq = lane & 31, h = lane >> 5;
    const int rw = rblk + w * 32;

    // x fragments hi/lo, split in registers
    s8v xhf[8], xlf[8];
    #pragma unroll
    for (int s = 0; s < 8; ++s) {
        const float* xp = &x[(size_t)(rw + lq) * NE + s * 16 + h * 8];
        float4 a = *(const float4*)xp;
        float4 b = *(const float4*)(xp + 4);
        unsigned int h0 = pkbf(a.x, a.y), h1 = pkbf(a.z, a.w);
        unsigned int h2 = pkbf(b.x, b.y), h3 = pkbf(b.z, b.w);
        float l0 = a.x - __uint_as_float(h0 << 16);
        float l1 = a.y - __uint_as_float(h0 & 0xFFFF0000u);
        float l2 = a.z - __uint_as_float(h1 << 16);
        float l3 = a.w - __uint_as_float(h1 & 0xFFFF0000u);
        float l4 = b.x - __uint_as_float(h2 << 16);
        float l5 = b.y - __uint_as_float(h2 & 0xFFFF0000u);
        float l6 = b.z - __uint_as_float(h3 << 16);
        float l7 = b.w - __uint_as_float(h3 & 0xFFFF0000u);
        union { uint4 u; s8v v; } H, L;
        H.u = make_uint4(h0, h1, h2, h3);
        L.u = make_uint4(pkbf(l0, l1), pkbf(l2, l3), pkbf(l4, l5), pkbf(l6, l7));
        xhf[s] = H.v;
        xlf[s] = L.v;
    }

    fx16 acc[2];
    #pragma unroll
    for (int ot = 0; ot < 2; ++ot)
        #pragma unroll
        for (int i = 0; i < 16; ++i) acc[ot][i] = 0.f;

    #pragma unroll
    for (int s = 0; s < 8; ++s) {
        #pragma unroll
        for (int ot = 0; ot < 2; ++ot) {
            s8v wh = *(const s8v*)&WhL[(ot * 32 + lq) * 136 + s * 16 + h * 8];
            s8v wl = *(const s8v*)&WlL[(ot * 32 + lq) * 136 + s * 16 + h * 8];
            if (mat != 2) {
                acc[ot] = __builtin_amdgcn_mfma_f32_32x32x16_bf16(wh, xhf[s], acc[ot], 0, 0, 0);
                acc[ot] = __builtin_amdgcn_mfma_f32_32x32x16_bf16(wh, xlf[s], acc[ot], 0, 0, 0);
                acc[ot] = __builtin_amdgcn_mfma_f32_32x32x16_bf16(wl, xhf[s], acc[ot], 0, 0, 0);
            } else {
                acc[ot] = __builtin_amdgcn_mfma_f32_32x32x16_bf16(xhf[s], wh, acc[ot], 0, 0, 0);
                acc[ot] = __builtin_amdgcn_mfma_f32_32x32x16_bf16(xlf[s], wh, acc[ot], 0, 0, 0);
                acc[ot] = __builtin_amdgcn_mfma_f32_32x32x16_bf16(xhf[s], wl, acc[ot], 0, 0, 0);
            }
        }
    }

    unsigned short* st = &stg[w * 2560];   // private per wave; no barrier needed

    if (mat != 2) {
        // acc: lane owns x-row (rw+lq), regs span o. Stage [row][o] (stride 72),
        // then coalesced 16B stores of row-major out.
        #pragma unroll
        for (int ot = 0; ot < 2; ++ot)
            #pragma unroll
            for (int g = 0; g < 4; ++g) {
                int col = ot * 32 + 4 * h + 8 * g;
                float4 bb = *(const float4*)&bias[o0 + col];
                unsigned int p0 = pkbf((acc[ot][4 * g + 0] + bb.x) * osc,
                                       (acc[ot][4 * g + 1] + bb.y) * osc);
                unsigned int p1 = pkbf((acc[ot][4 * g + 2] + bb.z) * osc,
                                       (acc[ot][4 * g + 3] + bb.w) * osc);
                *(uint2*)&st[lq * 72 + col] = make_uint2(p0, p1);
            }
        const int r2 = lane >> 3, cg = (lane & 7) * 8;
        #pragma unroll
        for (int p = 0; p < 4; ++p) {
            int rr = p * 8 + r2;
            uint4 v4 = *(uint4*)&st[rr * 72 + cg];
            *(uint4*)&out[(size_t)(rw + rr) * NE + o0 + cg] = v4;
        }
    } else {
        // acc: lane owns d (o0+ot*32+lq), regs span key. Stage [d][key]
        // (stride 40), then coalesced 16B stores along keys of Vt[d][key].
        #pragma unroll
        for (int ot = 0; ot < 2; ++ot) {
            int d = ot * 32 + lq;
            float bv = bias[o0 + d];
            #pragma unroll
            for (int g = 0; g < 4; ++g) {
                unsigned int p0 = pkbf(acc[ot][4 * g + 0] + bv, acc[ot][4 * g + 1] + bv);
                unsigned int p1 = pkbf(acc[ot][4 * g + 2] + bv, acc[ot][4 * g + 3] + bv);
                *(uint2*)&st[d * 40 + 4 * h + 8 * g] = make_uint2(p0, p1);
            }
        }
        const int bb_ = rw >> 13, rwk = rw & (NS - 1);
        const int d2 = lane >> 2, kg = (lane & 3) * 8;
        #pragma unroll
        for (int p = 0; p < 4; ++p) {
            int dd = p * 16 + d2;
            uint4 v4 = *(uint4*)&st[dd * 40 + kg];
            *(uint4*)&out[(((size_t)(bb_ * NE + o0 + dd)) << 13) + rwk + kg] = v4;
        }
    }
}

// ---------------------------------------------------------------------------
// bf16 MFMA flash attention (r11 structure), max-free softmax, perm-pack P.
// grid 512, block 256.
// ---------------------------------------------------------------------------
__global__ __launch_bounds__(256, 2)
void attn_kernel(const unsigned short* __restrict__ qkv,
                 _Float16* __restrict__ pd,      // d_out as fp16 partials
                 _Float16* __restrict__ pw,      // ws partials
                 float* __restrict__ ml)         // ws [q*4+ks] = l
{
    __shared__ unsigned short kbuf[2][64 * 128];
    __shared__ unsigned short vbuf[2][64 * 128];

    const int t  = threadIdx.x;
    const int id = blockIdx.x;
    const int ks = id & 3;
    const int b  = (id >> 2) & 1;
    const int T  = id >> 3;

    const unsigned short* Qg = qkv;
    const unsigned short* Kg = qkv + (size_t)NROWS * NE;
    const unsigned short* Vb = qkv + (size_t)2 * NROWS * NE + ((size_t)b << 20);

    const int w = t >> 6, lane = t & 63, lq = lane & 31, h = lane >> 5;
    const int qbw = b * NS + T * 128 + w * 32;
    const size_t kvb = (size_t)b * NS * NE;
    const int kq0 = ks * 2048;

    s8v qf[8];
    #pragma unroll
    for (int s = 0; s < 8; ++s)
        qf[s] = *(const s8v*)(Qg + (size_t)(qbw + lq) * NE + s * 16 + h * 8);

    fx16 acc[4];
    #pragma unroll
    for (int dt = 0; dt < 4; ++dt)
        #pragma unroll
        for (int i = 0; i < 16; ++i) acc[dt][i] = 0.f;

    float l = 0.f;

    auto stage = [&](int r, int buf) {
        const int base = kq0 + r * 64;
        if (w < 2) {
            #pragma unroll
            for (int j = 0; j < 8; ++j) {
                int i = 8 * w + j;
                int keyl = 4 * i + (lane >> 4);
                int c = (lane & 15) ^ (keyl & 7);
                const unsigned short* g =
                    Kg + kvb + (size_t)(base + keyl) * NE + c * 8;
                __builtin_amdgcn_global_load_lds((as1c*)g,
                    (as3t*)&kbuf[buf][i * 512], 16, 0, 0);
            }
        } else {
            #pragma unroll
            for (int j = 0; j < 8; ++j) {
                int i = 8 * (w - 2) + j;
                int d = 8 * i + (lane >> 3);
                int g = (lane & 7) ^ (d & 7);
                const unsigned short* gp =
                    Vb + ((size_t)d << 13) + base + g * 8;
                __builtin_amdgcn_global_load_lds((as1c*)gp,
                    (as3t*)&vbuf[buf][i * 512], 16, 0, 0);
            }
        }
    };

    stage(0, 0);
    __syncthreads();

#define PEX(i) (st2[(i) >> 4][(i) & 15])
    int buf = 0;
    const int swz = (lq & 7) * 8;

    for (int r = 0; r < 32; ++r) {
        if (r < 31) stage(r + 1, buf ^ 1);

        // ---- GEMM1: S^T[64 key][32 q] = K.Q^T from swizzled LDS ----
        fx16 st2[2];
        #pragma unroll
        for (int mt = 0; mt < 2; ++mt)
            #pragma unroll
            for (int i = 0; i < 16; ++i) st2[mt][i] = 0.f;
        #pragma unroll
        for (int s = 0; s < 8; ++s) {
            int co = ((s * 2 + h) * 8) ^ swz;
            s8v a0 = *(const s8v*)&kbuf[buf][lq * 128 + co];
            s8v a1 = *(const s8v*)&kbuf[buf][(32 + lq) * 128 + co];
            st2[0] = __builtin_amdgcn_mfma_f32_32x32x16_bf16(a0, qf[s], st2[0], 0, 0, 0);
            st2[1] = __builtin_amdgcn_mfma_f32_32x32x16_bf16(a1, qf[s], st2[1], 0, 0, 0);
        }

        // ---- max-free softmax: P = exp(score), 4-chain l sum ----
        float s0 = 0.f, s1 = 0.f, s2 = 0.f, s3 = 0.f;
        #pragma unroll
        for (int i = 0; i < 32; i += 4) {
            PEX(i + 0) = __expf(PEX(i + 0)); s0 += PEX(i + 0);
            PEX(i + 1) = __expf(PEX(i + 1)); s1 += PEX(i + 1);
            PEX(i + 2) = __expf(PEX(i + 2)); s2 += PEX(i + 2);
            PEX(i + 3) = __expf(PEX(i + 3)); s3 += PEX(i + 3);
        }
        float lsum = (s0 + s1) + (s2 + s3);
        lsum += __shfl_xor(lsum, 32);
        l += lsum;

        // ---- GEMM2: O += P.V; P perm-pack + half-exchange; V from LDS ----
        #pragma unroll
        for (int s2i = 0; s2i < 4; ++s2i) {
            unsigned int P0 = pkhi(PEX(s2i * 8 + 0), PEX(s2i * 8 + 1));
            unsigned int P1 = pkhi(PEX(s2i * 8 + 2), PEX(s2i * 8 + 3));
            unsigned int P2 = pkhi(PEX(s2i * 8 + 4), PEX(s2i * 8 + 5));
            unsigned int P3 = pkhi(PEX(s2i * 8 + 6), PEX(s2i * 8 + 7));
            unsigned int X0 = (unsigned int)__shfl_xor((int)P0, 32);
            unsigned int X1 = (unsigned int)__shfl_xor((int)P1, 32);
            unsigned int X2 = (unsigned int)__shfl_xor((int)P2, 32);
            unsigned int X3 = (unsigned int)__shfl_xor((int)P3, 32);
            union { unsigned int u[4]; s8v v; } pf;
            pf.u[0] = h ? X2 : P0;
            pf.u[1] = h ? X3 : P1;
            pf.u[2] = h ? P2 : X0;
            pf.u[3] = h ? P3 : X1;
            int go = ((s2i * 2 + h) * 8) ^ swz;
            #pragma unroll
            for (int dt = 0; dt < 4; ++dt) {
                s8v vf = *(const s8v*)&vbuf[buf][(lq + 32 * dt) * 64 + go];
                acc[dt] = __builtin_amdgcn_mfma_f32_32x32x16_bf16(pf.v, vf, acc[dt], 0, 0, 0);
            }
        }

        __syncthreads();
        buf ^= 1;
    }
#undef PEX

    // ---- epilogue: normalize by own l, store fp16 partial + l ----
    if (lane < 32)
        ml[(size_t)(qbw + lq) * 4 + ks] = l;

    float invl = 1.0f / l;
    _Float16* P = (ks < 2) ? pd : pw;
    const int slot = (ks & 1) * 128;
    #pragma unroll
    for (int rg = 0; rg < 16; ++rg) {
        int row = (rg & 3) + 8 * (rg >> 2) + 4 * h;
        float sc = __shfl(invl, row);
        size_t rb = (size_t)(qbw + row) * 256 + slot;
        #pragma unroll
        for (int dt = 0; dt < 4; ++dt)
            P[rb + lq + 32 * dt] = (_Float16)(acc[dt][rg] * sc);
    }
}

// ---------------------------------------------------------------------------
// 4-way l-weighted merge. grid 1024, block 256.
// ---------------------------------------------------------------------------
__global__ __launch_bounds__(256, 2)
void merge_kernel(const _Float16* __restrict__ pw,
                  const float* __restrict__ ml,
                  float* __restrict__ outp)
{
    const int gi = blockIdx.x * 256 + threadIdx.x;
    const int q = gi >> 4, d0 = (gi & 15) * 8;
    const _Float16* pd = (const _Float16*)outp;

    uint4 u0 = *(const uint4*)&pd[(size_t)q * 256 + d0];
    uint4 u1 = *(const uint4*)&pd[(size_t)q * 256 + 128 + d0];
    uint4 u2 = *(const uint4*)&pw[(size_t)q * 256 + d0];
    uint4 u3 = *(const uint4*)&pw[(size_t)q * 256 + 128 + d0];
    float l0 = ml[q * 4 + 0], l1 = ml[q * 4 + 1];
    float l2 = ml[q * 4 + 2], l3 = ml[q * 4 + 3];

    float inv = 1.f / (l0 + l1 + l2 + l3);
    float a0 = l0 * inv, a1 = l1 * inv, a2 = l2 * inv, a3 = l3 * inv;

    union { uint4 u; _Float16 hh[8]; } c0, c1, c2, c3;
    c0.u = u0; c1.u = u1; c2.u = u2; c3.u = u3;
    float ov[8];
    #pragma unroll
    for (int e = 0; e < 8; ++e)
        ov[e] = (float)c0.hh[e] * a0 + (float)c1.hh[e] * a1 +
                (float)c2.hh[e] * a2 + (float)c3.hh[e] * a3;

    *(float4*)&outp[(size_t)q * 128 + d0]     = *(float4*)&ov[0];
    *(float4*)&outp[(size_t)q * 128 + d0 + 4] = *(float4*)&ov[4];
}

// ---------------------------------------------------------------------------
extern "C" void kernel_launch(void* const* d_in, const int* in_sizes, int n_in,
                              void* d_out, int out_size, void* d_ws, size_t ws_size,
                              hipStream_t stream)
{
    const float* x  = (const float*)d_in[0];
    const float* Wq = (const float*)d_in[1];
    const float* bq = (const float*)d_in[2];
    const float* Wk = (const float*)d_in[3];
    const float* bk = (const float*)d_in[4];
    const float* Wv = (const float*)d_in[5];
    const float* bv = (const float*)d_in[6];
    float* out = (float*)d_out;

    unsigned char* ws = (unsigned char*)d_ws;
    unsigned short* qkv = (unsigned short*)ws;                       // 12.58 MB
    _Float16* pw = (_Float16*)(ws + (size_t)3 * NROWS * NE * 2);     // 8.39 MB
    float* mlp = (float*)(ws + (size_t)3 * NROWS * NE * 2
                             + (size_t)NROWS * 256 * 2);             // 0.26 MB

    dim3 g1(NROWS / 128, 3, 2);
    qkv_kernel<<<g1, 256, 0, stream>>>(x, Wq, bq, Wk, bk, Wv, bv, qkv);

    attn_kernel<<<512, 256, 0, stream>>>(qkv, (_Float16*)d_out, pw, mlp);
    merge_kernel<<<1024, 256, 0, stream>>>(pw, mlp, out);
}